// Round 1
// baseline (1000.702 us; speedup 1.0000x reference)
//
#include <hip/hip_runtime.h>
#include <cfloat>
#include <climits>
#include <cmath>

constexpr int N_ = 100000;
constexpr int E_ = 800000;

// ---------------- init ----------------
__global__ void k_init_minmax(int* minmax) {
    minmax[0] = INT_MAX;
    minmax[1] = INT_MIN;
}

// time encoding + count init + t min/max
__global__ __launch_bounds__(256) void k_prep(const int* __restrict__ ts, float* __restrict__ te,
                                              int* __restrict__ count, int* __restrict__ minmax) {
    // freqs[j] = 10^(-j/2)  (== exp(-(2j) * ln(10000)/16))
    const float FRQ[8] = {1.0f, 0.31622776601683794f, 0.1f, 0.031622776601683794f,
                          0.01f, 0.0031622776601683794f, 0.001f, 0.00031622776601683794f};
    int n = blockIdx.x * 256 + threadIdx.x;
    int tv_min = INT_MAX, tv_max = INT_MIN;
    if (n < N_) {
        int tv = ts[n];
        tv_min = tv; tv_max = tv;
        count[n] = 1;  // self loop
        float tf = (float)tv;
#pragma unroll
        for (int j = 0; j < 8; ++j) {
            float ph = tf * FRQ[j];
            te[n * 16 + j] = sinf(ph);
            te[n * 16 + 8 + j] = cosf(ph);
        }
    }
#pragma unroll
    for (int o = 32; o >= 1; o >>= 1) {
        tv_min = min(tv_min, __shfl_xor(tv_min, o));
        tv_max = max(tv_max, __shfl_xor(tv_max, o));
    }
    if ((threadIdx.x & 63) == 0) {
        atomicMin(&minmax[0], tv_min);
        atomicMax(&minmax[1], tv_max);
    }
}

__global__ __launch_bounds__(256) void k_count(const int* __restrict__ ei, int* __restrict__ count) {
    int e = blockIdx.x * 256 + threadIdx.x;
    if (e < E_) atomicAdd(&count[ei[E_ + e]], 1);
}

// two-level exclusive scan of count[N] -> indptr, plus self-loop scatter + cursor init
__global__ __launch_bounds__(1024) void k_scan_a(const int* __restrict__ count, int* __restrict__ cbase) {
    constexpr int CHK = 98;  // 1024*98 >= 100000
    int t = threadIdx.x;
    int base = t * CHK;
    int sum = 0;
    for (int i = 0; i < CHK; ++i) {
        int idx = base + i;
        if (idx < N_) sum += count[idx];
    }
    __shared__ int sc[1024];
    sc[t] = sum;
    __syncthreads();
    for (int o = 1; o < 1024; o <<= 1) {
        int v = (t >= o) ? sc[t - o] : 0;
        __syncthreads();
        sc[t] += v;
        __syncthreads();
    }
    cbase[t] = sc[t] - sum;  // exclusive
    if (t == 1023) cbase[1024] = sc[1023];
}

__global__ __launch_bounds__(256) void k_scan_b(const int* __restrict__ count, const int* __restrict__ cbase,
                                                int* __restrict__ indptr, int* __restrict__ srcs,
                                                int* __restrict__ cursor) {
    constexpr int CHK = 98;
    int t = blockIdx.x * 256 + threadIdx.x;
    if (t >= 1024) return;
    int run = cbase[t];
    int base = t * CHK;
    for (int i = 0; i < CHK; ++i) {
        int idx = base + i;
        if (idx < N_) {
            indptr[idx] = run;
            srcs[run] = idx;       // self loop first
            cursor[idx] = run + 1;
            run += count[idx];
        }
    }
    if (t == 0) indptr[N_] = cbase[1024];
}

__global__ __launch_bounds__(256) void k_scatter(const int* __restrict__ ei, int* __restrict__ cursor,
                                                 int* __restrict__ srcs) {
    int e = blockIdx.x * 256 + threadIdx.x;
    if (e < E_) {
        int s = ei[e];
        int d = ei[E_ + e];
        int p = atomicAdd(&cursor[d], 1);
        srcs[p] = s;
    }
}

__global__ __launch_bounds__(256) void k_gate(const int* __restrict__ ts, const int* __restrict__ minmax,
                                              const float* __restrict__ gw1, const float* __restrict__ gb1,
                                              const float* __restrict__ gw2, const float* __restrict__ gb2,
                                              float* __restrict__ gate) {
    int n = blockIdx.x * 256 + threadIdx.x;
    if (n >= N_) return;
    float mn = (float)minmax[0], mx = (float)minmax[1];
    float age = ((float)ts[n] - mn) / fmaxf(mx - mn, 1.0f);
    float o = gb2[0];
#pragma unroll
    for (int j = 0; j < 16; ++j) {
        float hj = fmaxf(age * gw1[j] + gb1[j], 0.f);
        o += hj * gw2[j];
    }
    gate[n] = 1.f / (1.f + __expf(-o));
}

// ---------------- fp32 GEMM: C = act(A@W + b), 128-row x M-col tile ----------------
template <int K, int M, bool RELU, bool BIAS, bool SRCTE>
__global__ __launch_bounds__(256) void k_gemm(const float* __restrict__ A, const float* __restrict__ te,
                                              const float* __restrict__ W, const float* __restrict__ bias,
                                              float* __restrict__ Cout) {
    constexpr int GR = 128;
    constexpr int KC = 16;
    constexpr int CT = M / 8;  // cols per thread
    __shared__ float As[KC][GR + 4];
    __shared__ float Ws[KC][M];
    const int r0 = blockIdx.x * GR;
    const int tid = threadIdx.x;
    const int tx = tid & 7;
    const int ty = tid >> 3;
    float acc[4][CT];
#pragma unroll
    for (int i = 0; i < 4; ++i)
#pragma unroll
        for (int j = 0; j < CT; ++j) acc[i][j] = 0.f;

    for (int k0 = 0; k0 < K; k0 += KC) {
        __syncthreads();
#pragma unroll
        for (int i = 0; i < (GR * KC) / 256; ++i) {
            int e = tid + i * 256;
            int row = e >> 4;
            int kk = e & 15;
            int gr = r0 + row;
            float v = 0.f;
            if (gr < N_) {
                int kg = k0 + kk;
                if (SRCTE) {
                    v = (kg < 128) ? A[gr * 128 + kg] : te[gr * 16 + (kg - 128)];
                } else {
                    v = A[(size_t)gr * K + kg];
                }
            }
            As[kk][row] = v;
        }
#pragma unroll
        for (int i = 0; i < (KC * M) / 256; ++i) {
            int e = tid + i * 256;
            int kk = e / M;
            int col = e - kk * M;
            Ws[kk][col] = W[(k0 + kk) * M + col];
        }
        __syncthreads();
#pragma unroll
        for (int kk = 0; kk < KC; ++kk) {
            float4 a = *(const float4*)&As[kk][ty * 4];
            float av[4] = {a.x, a.y, a.z, a.w};
            float wv[CT];
#pragma unroll
            for (int q = 0; q < CT / 4; ++q) {
                float4 w = *(const float4*)&Ws[kk][tx * CT + q * 4];
                wv[q * 4 + 0] = w.x; wv[q * 4 + 1] = w.y;
                wv[q * 4 + 2] = w.z; wv[q * 4 + 3] = w.w;
            }
#pragma unroll
            for (int i = 0; i < 4; ++i)
#pragma unroll
                for (int j = 0; j < CT; ++j) acc[i][j] = fmaf(av[i], wv[j], acc[i][j]);
        }
    }
#pragma unroll
    for (int i = 0; i < 4; ++i) {
        int gr = r0 + ty * 4 + i;
        if (gr < N_) {
#pragma unroll
            for (int q = 0; q < CT / 4; ++q) {
                float4 v;
                float* vv = (float*)&v;
#pragma unroll
                for (int u = 0; u < 4; ++u) {
                    int j = q * 4 + u;
                    float x = acc[i][j];
                    if (BIAS) x += bias[tx * CT + j];
                    if (RELU) x = fmaxf(x, 0.f);
                    vv[u] = x;
                }
                *(float4*)&Cout[(size_t)gr * M + tx * CT + q * 4] = v;
            }
        }
    }
}

// per-node attention logits: al_s/al_d[n][head] = sum_c h2[n][head*32+c]*att[head][c]
__global__ __launch_bounds__(128) void k_al(const float* __restrict__ h2, const float* __restrict__ asrc,
                                            const float* __restrict__ adst, float* __restrict__ al_s,
                                            float* __restrict__ al_d) {
    int n = blockIdx.x;
    int c = threadIdx.x;
    float v = h2[(size_t)n * 128 + c];
    float ps = v * asrc[c];
    float pd = v * adst[c];
#pragma unroll
    for (int o = 16; o >= 1; o >>= 1) {
        ps += __shfl_xor(ps, o);
        pd += __shfl_xor(pd, o);
    }
    if ((c & 31) == 0) {
        al_s[n * 4 + (c >> 5)] = ps;
        al_d[n * 4 + (c >> 5)] = pd;
    }
}

// GAT aggregation per dst node: softmax over incoming edges + weighted sum + BN/ELU/gate
__global__ __launch_bounds__(128) void k_gat(const int* __restrict__ indptr, const int* __restrict__ srcs,
                                             const float* __restrict__ al_s, const float* __restrict__ al_d,
                                             const float* __restrict__ h2, const float* __restrict__ convb,
                                             const float* __restrict__ gamma, const float* __restrict__ beta,
                                             const float* __restrict__ mean, const float* __restrict__ var,
                                             const float* __restrict__ gate, float* __restrict__ hout) {
    int n = blockIdx.x;
    int t = threadIdx.x;
    int start = indptr[n], end = indptr[n + 1];
    float4 aldv4 = *(const float4*)&al_d[n * 4];
    float aldv[4] = {aldv4.x, aldv4.y, aldv4.z, aldv4.w};

    // phase 1: per-head max
    float mx[4] = {-FLT_MAX, -FLT_MAX, -FLT_MAX, -FLT_MAX};
    for (int p = start + t; p < end; p += 128) {
        int s = srcs[p];
        float4 als = *(const float4*)&al_s[s * 4];
        float av[4] = {als.x, als.y, als.z, als.w};
#pragma unroll
        for (int h = 0; h < 4; ++h) {
            float a = av[h] + aldv[h];
            a = a > 0.f ? a : 0.2f * a;
            mx[h] = fmaxf(mx[h], a);
        }
    }
    __shared__ float red[2][8];
    int wv = t >> 6;
    int lane = t & 63;
#pragma unroll
    for (int h = 0; h < 4; ++h) {
        float m = mx[h];
#pragma unroll
        for (int o = 32; o >= 1; o >>= 1) m = fmaxf(m, __shfl_xor(m, o));
        if (lane == 0) red[wv][h] = m;
    }
    __syncthreads();
    float mh[4];
#pragma unroll
    for (int h = 0; h < 4; ++h) mh[h] = fmaxf(red[0][h], red[1][h]);

    // phase 2: sum of exp
    float sm[4] = {0.f, 0.f, 0.f, 0.f};
    for (int p = start + t; p < end; p += 128) {
        int s = srcs[p];
        float4 als = *(const float4*)&al_s[s * 4];
        float av[4] = {als.x, als.y, als.z, als.w};
#pragma unroll
        for (int h = 0; h < 4; ++h) {
            float a = av[h] + aldv[h];
            a = a > 0.f ? a : 0.2f * a;
            sm[h] += __expf(a - mh[h]);
        }
    }
#pragma unroll
    for (int h = 0; h < 4; ++h) {
        float s = sm[h];
#pragma unroll
        for (int o = 32; o >= 1; o >>= 1) s += __shfl_xor(s, o);
        if (lane == 0) red[wv][4 + h] = s;
    }
    __syncthreads();
    float den[4];
#pragma unroll
    for (int h = 0; h < 4; ++h) den[h] = red[0][4 + h] + red[1][4 + h] + 1e-16f;

    // phase 3: weighted message sum, channel per thread
    int head = t >> 5;
    float aldh = aldv[head];
    float mhh = mh[head];
    float accv = 0.f;
    for (int p = start; p < end; ++p) {
        int s = srcs[p];
        float a = al_s[s * 4 + head] + aldh;
        a = a > 0.f ? a : 0.2f * a;
        float w = __expf(a - mhh);
        accv += w * h2[(size_t)s * 128 + t];
    }
    float val = accv / den[head] + convb[t];
    float sc = gamma[t] * rsqrtf(var[t] + 1e-5f);
    val = (val - mean[t]) * sc + beta[t];
    val = val > 0.f ? val : expm1f(val);
    val *= gate[n];
    hout[(size_t)n * 128 + t] = val;
}

// head layer 2: (N,64) @ (64,2) + b2
__global__ __launch_bounds__(256) void k_head2(const float* __restrict__ hh, const float* __restrict__ W2,
                                               const float* __restrict__ b2, float* __restrict__ out) {
    __shared__ float w[128];
    __shared__ float bsh[2];
    if (threadIdx.x < 128) w[threadIdx.x] = W2[threadIdx.x];
    if (threadIdx.x < 2) bsh[threadIdx.x] = b2[threadIdx.x];
    __syncthreads();
    int r = blockIdx.x * 256 + threadIdx.x;
    if (r >= N_) return;
    float a0 = bsh[0], a1 = bsh[1];
    const float4* hv = (const float4*)&hh[(size_t)r * 64];
#pragma unroll
    for (int q = 0; q < 16; ++q) {
        float4 v = hv[q];
        int k = q * 4;
        a0 += v.x * w[2 * k + 0] + v.y * w[2 * k + 2] + v.z * w[2 * k + 4] + v.w * w[2 * k + 6];
        a1 += v.x * w[2 * k + 1] + v.y * w[2 * k + 3] + v.z * w[2 * k + 5] + v.w * w[2 * k + 7];
    }
    ((float2*)out)[r] = make_float2(a0, a1);
}

extern "C" void kernel_launch(void* const* d_in, const int* in_sizes, int n_in,
                              void* d_out, int out_size, void* d_ws, size_t ws_size,
                              hipStream_t stream) {
    const float* x       = (const float*)d_in[0];
    const int*   ei      = (const int*)d_in[1];
    const int*   ts      = (const int*)d_in[2];
    const float* proj_w  = (const float*)d_in[3];
    const float* proj_b  = (const float*)d_in[4];
    const float* conv_w  = (const float*)d_in[5];
    const float* conv_b  = (const float*)d_in[6];
    const float* att_src = (const float*)d_in[7];
    const float* att_dst = (const float*)d_in[8];
    const float* bn_g    = (const float*)d_in[9];
    const float* bn_b    = (const float*)d_in[10];
    const float* bn_m    = (const float*)d_in[11];
    const float* bn_v    = (const float*)d_in[12];
    const float* gw1     = (const float*)d_in[13];
    const float* gb1     = (const float*)d_in[14];
    const float* gw2     = (const float*)d_in[15];
    const float* gb2     = (const float*)d_in[16];
    const float* hw1     = (const float*)d_in[17];
    const float* hb1     = (const float*)d_in[18];
    const float* hw2     = (const float*)d_in[19];
    const float* hb2     = (const float*)d_in[20];
    float* out = (float*)d_out;

    float* ws   = (float*)d_ws;
    float* h    = ws;
    float* h2   = h + (size_t)N_ * 128;
    float* te   = h2 + (size_t)N_ * 128;
    float* al_s = te + (size_t)N_ * 16;
    float* al_d = al_s + (size_t)N_ * 4;
    float* gate = al_d + (size_t)N_ * 4;
    int* indptr = (int*)(gate + N_);
    int* srcs   = indptr + (N_ + 1);
    int* count  = srcs + (N_ + E_);
    int* cursor = count + N_;
    int* cbase  = cursor + N_;
    int* minmax = cbase + 1025;

    k_init_minmax<<<1, 1, 0, stream>>>(minmax);
    k_prep<<<(N_ + 255) / 256, 256, 0, stream>>>(ts, te, count, minmax);
    k_count<<<(E_ + 255) / 256, 256, 0, stream>>>(ei, count);
    k_scan_a<<<1, 1024, 0, stream>>>(count, cbase);
    k_scan_b<<<4, 256, 0, stream>>>(count, cbase, indptr, srcs, cursor);
    k_scatter<<<(E_ + 255) / 256, 256, 0, stream>>>(ei, cursor, srcs);
    k_gate<<<(N_ + 255) / 256, 256, 0, stream>>>(ts, minmax, gw1, gb1, gw2, gb2, gate);

    k_gemm<144, 128, true, true, true><<<782, 256, 0, stream>>>(x, te, proj_w, proj_b, h);
    for (int l = 0; l < 2; ++l) {
        k_gemm<128, 128, false, false, false><<<782, 256, 0, stream>>>(h, nullptr, conv_w + l * 128 * 128,
                                                                       nullptr, h2);
        k_al<<<N_, 128, 0, stream>>>(h2, att_src + l * 128, att_dst + l * 128, al_s, al_d);
        k_gat<<<N_, 128, 0, stream>>>(indptr, srcs, al_s, al_d, h2, conv_b + l * 128,
                                      bn_g + l * 128, bn_b + l * 128, bn_m + l * 128, bn_v + l * 128,
                                      gate, h);
    }
    k_gemm<128, 64, true, true, false><<<782, 256, 0, stream>>>(h, nullptr, hw1, hb1, h2);
    k_head2<<<(N_ + 255) / 256, 256, 0, stream>>>(h2, hw2, hb2, out);
}

// Round 2
// 787.215 us; speedup vs baseline: 1.2712x; 1.2712x over previous
//
#include <hip/hip_runtime.h>
#include <cfloat>
#include <climits>
#include <cmath>

constexpr int N_ = 100000;
constexpr int E_ = 800000;

// ---------------- init ----------------
__global__ void k_init_minmax(int* minmax) {
    minmax[0] = INT_MAX;
    minmax[1] = INT_MIN;
}

// time encoding + count init + t min/max
__global__ __launch_bounds__(256) void k_prep(const int* __restrict__ ts, float* __restrict__ te,
                                              int* __restrict__ count, int* __restrict__ minmax) {
    const float FRQ[8] = {1.0f, 0.31622776601683794f, 0.1f, 0.031622776601683794f,
                          0.01f, 0.0031622776601683794f, 0.001f, 0.00031622776601683794f};
    int n = blockIdx.x * 256 + threadIdx.x;
    int tv_min = INT_MAX, tv_max = INT_MIN;
    if (n < N_) {
        int tv = ts[n];
        tv_min = tv; tv_max = tv;
        count[n] = 1;  // self loop
        float tf = (float)tv;
#pragma unroll
        for (int j = 0; j < 8; ++j) {
            float ph = tf * FRQ[j];
            te[n * 16 + j] = sinf(ph);
            te[n * 16 + 8 + j] = cosf(ph);
        }
    }
#pragma unroll
    for (int o = 32; o >= 1; o >>= 1) {
        tv_min = min(tv_min, __shfl_xor(tv_min, o));
        tv_max = max(tv_max, __shfl_xor(tv_max, o));
    }
    if ((threadIdx.x & 63) == 0) {
        atomicMin(&minmax[0], tv_min);
        atomicMax(&minmax[1], tv_max);
    }
}

__global__ __launch_bounds__(256) void k_count(const int* __restrict__ ei, int* __restrict__ count) {
    int e = blockIdx.x * 256 + threadIdx.x;
    if (e < E_) atomicAdd(&count[ei[E_ + e]], 1);
}

__global__ __launch_bounds__(1024) void k_scan_a(const int* __restrict__ count, int* __restrict__ cbase) {
    constexpr int CHK = 98;
    int t = threadIdx.x;
    int base = t * CHK;
    int sum = 0;
    for (int i = 0; i < CHK; ++i) {
        int idx = base + i;
        if (idx < N_) sum += count[idx];
    }
    __shared__ int sc[1024];
    sc[t] = sum;
    __syncthreads();
    for (int o = 1; o < 1024; o <<= 1) {
        int v = (t >= o) ? sc[t - o] : 0;
        __syncthreads();
        sc[t] += v;
        __syncthreads();
    }
    cbase[t] = sc[t] - sum;
    if (t == 1023) cbase[1024] = sc[1023];
}

__global__ __launch_bounds__(256) void k_scan_b(const int* __restrict__ count, const int* __restrict__ cbase,
                                                int* __restrict__ indptr, int* __restrict__ srcs,
                                                int* __restrict__ cursor) {
    constexpr int CHK = 98;
    int t = blockIdx.x * 256 + threadIdx.x;
    if (t >= 1024) return;
    int run = cbase[t];
    int base = t * CHK;
    for (int i = 0; i < CHK; ++i) {
        int idx = base + i;
        if (idx < N_) {
            indptr[idx] = run;
            srcs[run] = idx;
            cursor[idx] = run + 1;
            run += count[idx];
        }
    }
    if (t == 0) indptr[N_] = cbase[1024];
}

__global__ __launch_bounds__(256) void k_scatter(const int* __restrict__ ei, int* __restrict__ cursor,
                                                 int* __restrict__ srcs) {
    int e = blockIdx.x * 256 + threadIdx.x;
    if (e < E_) {
        int s = ei[e];
        int d = ei[E_ + e];
        int p = atomicAdd(&cursor[d], 1);
        srcs[p] = s;
    }
}

__global__ __launch_bounds__(256) void k_gate(const int* __restrict__ ts, const int* __restrict__ minmax,
                                              const float* __restrict__ gw1, const float* __restrict__ gb1,
                                              const float* __restrict__ gw2, const float* __restrict__ gb2,
                                              float* __restrict__ gate) {
    int n = blockIdx.x * 256 + threadIdx.x;
    if (n >= N_) return;
    float mn = (float)minmax[0], mx = (float)minmax[1];
    float age = ((float)ts[n] - mn) / fmaxf(mx - mn, 1.0f);
    float o = gb2[0];
#pragma unroll
    for (int j = 0; j < 16; ++j) {
        float hj = fmaxf(age * gw1[j] + gb1[j], 0.f);
        o += hj * gw2[j];
    }
    gate[n] = 1.f / (1.f + __expf(-o));
}

// ---------------- fused fp32 GEMM, 128-row tile, 8x8 per-thread blocking ----------------
// MODE 0: proj  (A=x concat te, +bias, relu)            -> Cout = h
// MODE 1: conv  (raw h2) + attention-logit epilogue     -> Cout = h2, al_s, al_d
// MODE 2: head  (+bias, relu, fused @w2+b2)             -> Cout = out (N,2)
template <int K, int M, int MODE>
__global__ __launch_bounds__(256) void k_gemm(const float* __restrict__ A, const float* __restrict__ te,
                                              const float* __restrict__ W, const float* __restrict__ bias,
                                              const float* __restrict__ asrc, const float* __restrict__ adst,
                                              const float* __restrict__ w2, const float* __restrict__ b2,
                                              float* __restrict__ Cout, float* __restrict__ al_s,
                                              float* __restrict__ al_d) {
    constexpr int GR = 128, KC = 16;
    constexpr int NS = M / 64;
    __shared__ float As[KC][GR + 4];
    __shared__ float Ws[KC][M];
    __shared__ float asl[128], adl[128];
    __shared__ float w2l[128];
    const int r0 = blockIdx.x * GR;
    const int tid = threadIdx.x;
    const int tx = tid & 15, ty = tid >> 4;
    if (MODE == 1 && tid < 128) { asl[tid] = asrc[tid]; adl[tid] = adst[tid]; }
    if (MODE == 2 && tid < 128) { w2l[tid] = w2[tid]; }
    float acc[8][NS * 4];
#pragma unroll
    for (int i = 0; i < 8; ++i)
#pragma unroll
        for (int j = 0; j < NS * 4; ++j) acc[i][j] = 0.f;

    for (int k0 = 0; k0 < K; k0 += KC) {
        __syncthreads();
        // stage A tile: float4 loads, transposed scalar LDS writes
#pragma unroll
        for (int i = 0; i < 2; ++i) {
            int f = tid * 2 + i;
            int row = f >> 2, fq = f & 3;
            int gr = r0 + row;
            float4 v = make_float4(0.f, 0.f, 0.f, 0.f);
            if (gr < N_) {
                if (MODE == 0) {
                    if (k0 < 128) v = *(const float4*)&A[gr * 128 + k0 + fq * 4];
                    else          v = *(const float4*)&te[gr * 16 + fq * 4];
                } else {
                    v = *(const float4*)&A[gr * K + k0 + fq * 4];
                }
            }
            As[fq * 4 + 0][row] = v.x;
            As[fq * 4 + 1][row] = v.y;
            As[fq * 4 + 2][row] = v.z;
            As[fq * 4 + 3][row] = v.w;
        }
        // stage W tile
#pragma unroll
        for (int i = 0; i < (KC * M / 4) / 256; ++i) {
            int f = tid + i * 256;
            int kk = f / (M / 4), c4 = f % (M / 4);
            *(float4*)&Ws[kk][c4 * 4] = *(const float4*)&W[(k0 + kk) * M + c4 * 4];
        }
        __syncthreads();
#pragma unroll
        for (int kk = 0; kk < KC; ++kk) {
            float4 a0 = *(const float4*)&As[kk][ty * 8];
            float4 a1 = *(const float4*)&As[kk][ty * 8 + 4];
            float av[8] = {a0.x, a0.y, a0.z, a0.w, a1.x, a1.y, a1.z, a1.w};
            float wv[NS * 4];
#pragma unroll
            for (int s = 0; s < NS; ++s) {
                float4 w = *(const float4*)&Ws[kk][s * 64 + tx * 4];
                wv[s * 4 + 0] = w.x; wv[s * 4 + 1] = w.y;
                wv[s * 4 + 2] = w.z; wv[s * 4 + 3] = w.w;
            }
#pragma unroll
            for (int i = 0; i < 8; ++i)
#pragma unroll
                for (int j = 0; j < NS * 4; ++j) acc[i][j] = fmaf(av[i], wv[j], acc[i][j]);
        }
    }

#pragma unroll
    for (int i = 0; i < 8; ++i) {
        int gr = r0 + ty * 8 + i;
        bool valid = gr < N_;
        if (MODE == 0) {
            if (valid) {
#pragma unroll
                for (int s = 0; s < NS; ++s) {
                    float4 v;
                    v.x = fmaxf(acc[i][s * 4 + 0] + bias[s * 64 + tx * 4 + 0], 0.f);
                    v.y = fmaxf(acc[i][s * 4 + 1] + bias[s * 64 + tx * 4 + 1], 0.f);
                    v.z = fmaxf(acc[i][s * 4 + 2] + bias[s * 64 + tx * 4 + 2], 0.f);
                    v.w = fmaxf(acc[i][s * 4 + 3] + bias[s * 64 + tx * 4 + 3], 0.f);
                    *(float4*)&Cout[gr * M + s * 64 + tx * 4] = v;
                }
            }
        } else if (MODE == 1) {
            if (valid) {
#pragma unroll
                for (int s = 0; s < NS; ++s) {
                    float4 v = make_float4(acc[i][s * 4 + 0], acc[i][s * 4 + 1],
                                           acc[i][s * 4 + 2], acc[i][s * 4 + 3]);
                    *(float4*)&Cout[gr * M + s * 64 + tx * 4] = v;
                }
            }
#pragma unroll
            for (int s = 0; s < NS; ++s) {
                float ps = 0.f, pd = 0.f;
#pragma unroll
                for (int q = 0; q < 4; ++q) {
                    int c = s * 64 + tx * 4 + q;
                    ps = fmaf(acc[i][s * 4 + q], asl[c], ps);
                    pd = fmaf(acc[i][s * 4 + q], adl[c], pd);
                }
#pragma unroll
                for (int o = 1; o <= 4; o <<= 1) {
                    ps += __shfl_xor(ps, o);
                    pd += __shfl_xor(pd, o);
                }
                if (valid && (tx & 7) == 0) {
                    int head = 2 * s + (tx >> 3);
                    al_s[gr * 4 + head] = ps;
                    al_d[gr * 4 + head] = pd;
                }
            }
        } else {
            float ps0 = 0.f, ps1 = 0.f;
#pragma unroll
            for (int q = 0; q < 4; ++q) {
                float hv = fmaxf(acc[i][q] + bias[tx * 4 + q], 0.f);
                int c = tx * 4 + q;
                ps0 = fmaf(hv, w2l[c * 2 + 0], ps0);
                ps1 = fmaf(hv, w2l[c * 2 + 1], ps1);
            }
#pragma unroll
            for (int o = 1; o <= 8; o <<= 1) {
                ps0 += __shfl_xor(ps0, o);
                ps1 += __shfl_xor(ps1, o);
            }
            if (valid && tx == 0) {
                *(float2*)&Cout[gr * 2] = make_float2(ps0 + b2[0], ps1 + b2[1]);
            }
        }
    }
}

// GAT aggregation: alpha computed ONCE per edge, weights cached in LDS,
// online-softmax across chunks, lean fma gather in phase 3.
__global__ __launch_bounds__(128) void k_gat(const int* __restrict__ indptr, const int* __restrict__ srcs,
                                             const float* __restrict__ al_s, const float* __restrict__ al_d,
                                             const float* __restrict__ h2, const float* __restrict__ convb,
                                             const float* __restrict__ gamma, const float* __restrict__ beta,
                                             const float* __restrict__ mean, const float* __restrict__ var,
                                             const float* __restrict__ gate, float* __restrict__ hout) {
    constexpr int CAP = 128;
    int n = blockIdx.x, t = threadIdx.x;
    int start = indptr[n], end = indptr[n + 1];
    int head = t >> 5, lane = t & 63, wv = t >> 6;
    float4 ad4 = *(const float4*)&al_d[n * 4];
    float adv[4] = {ad4.x, ad4.y, ad4.z, ad4.w};
    __shared__ int s_lds[CAP];
    __shared__ float w_lds[4][CAP];
    __shared__ float redA[2][4], redB[2][4];
    float M[4] = {-FLT_MAX, -FLT_MAX, -FLT_MAX, -FLT_MAX};
    float D[4] = {0.f, 0.f, 0.f, 0.f};
    float acc = 0.f;
    for (int c0 = start; c0 < end; c0 += CAP) {
        int cs = min(CAP, end - c0);
        float a[4];
        if (t < cs) {
            int s = srcs[c0 + t];
            s_lds[t] = s;
            float4 as4 = *(const float4*)&al_s[s * 4];
            float asv[4] = {as4.x, as4.y, as4.z, as4.w};
#pragma unroll
            for (int h = 0; h < 4; ++h) {
                float x = asv[h] + adv[h];
                a[h] = x > 0.f ? x : 0.2f * x;
            }
        } else {
#pragma unroll
            for (int h = 0; h < 4; ++h) a[h] = -FLT_MAX;
        }
        // block max per head
#pragma unroll
        for (int h = 0; h < 4; ++h) {
            float m = a[h];
#pragma unroll
            for (int o = 32; o >= 1; o >>= 1) m = fmaxf(m, __shfl_xor(m, o));
            if (lane == 0) redA[wv][h] = m;
        }
        __syncthreads();
        float f[4], Mn[4];
#pragma unroll
        for (int h = 0; h < 4; ++h) {
            float mx = fmaxf(redA[0][h], redA[1][h]);
            Mn[h] = fmaxf(M[h], mx);
            f[h] = __expf(M[h] - Mn[h]);
        }
        float wreg[4];
#pragma unroll
        for (int h = 0; h < 4; ++h) {
            wreg[h] = (t < cs) ? __expf(a[h] - Mn[h]) : 0.f;
            if (t < cs) w_lds[h][t] = wreg[h];
        }
        // block sum per head
#pragma unroll
        for (int h = 0; h < 4; ++h) {
            float sv = wreg[h];
#pragma unroll
            for (int o = 32; o >= 1; o >>= 1) sv += __shfl_xor(sv, o);
            if (lane == 0) redB[wv][h] = sv;
        }
        __syncthreads();
#pragma unroll
        for (int h = 0; h < 4; ++h) {
            D[h] = D[h] * f[h] + (redB[0][h] + redB[1][h]);
            M[h] = Mn[h];
        }
        // gather: acc = acc*f + sum_i w[i] * h2[src_i][t]
        const float* wrow = w_lds[head];
        float a0 = 0.f, a1 = 0.f;
        int i = 0;
        for (; i + 1 < cs; i += 2) {
            int s0 = s_lds[i], s1 = s_lds[i + 1];
            a0 = fmaf(wrow[i], h2[s0 * 128 + t], a0);
            a1 = fmaf(wrow[i + 1], h2[s1 * 128 + t], a1);
        }
        if (i < cs) a0 = fmaf(wrow[i], h2[s_lds[i] * 128 + t], a0);
        acc = acc * f[head] + (a0 + a1);
        __syncthreads();
    }
    float val = acc / (D[head] + 1e-16f) + convb[t];
    float sc = gamma[t] * rsqrtf(var[t] + 1e-5f);
    val = (val - mean[t]) * sc + beta[t];
    val = val > 0.f ? val : expm1f(val);
    val *= gate[n];
    hout[n * 128 + t] = val;
}

extern "C" void kernel_launch(void* const* d_in, const int* in_sizes, int n_in,
                              void* d_out, int out_size, void* d_ws, size_t ws_size,
                              hipStream_t stream) {
    const float* x       = (const float*)d_in[0];
    const int*   ei      = (const int*)d_in[1];
    const int*   ts      = (const int*)d_in[2];
    const float* proj_w  = (const float*)d_in[3];
    const float* proj_b  = (const float*)d_in[4];
    const float* conv_w  = (const float*)d_in[5];
    const float* conv_b  = (const float*)d_in[6];
    const float* att_src = (const float*)d_in[7];
    const float* att_dst = (const float*)d_in[8];
    const float* bn_g    = (const float*)d_in[9];
    const float* bn_b    = (const float*)d_in[10];
    const float* bn_m    = (const float*)d_in[11];
    const float* bn_v    = (const float*)d_in[12];
    const float* gw1     = (const float*)d_in[13];
    const float* gb1     = (const float*)d_in[14];
    const float* gw2     = (const float*)d_in[15];
    const float* gb2     = (const float*)d_in[16];
    const float* hw1     = (const float*)d_in[17];
    const float* hb1     = (const float*)d_in[18];
    const float* hw2     = (const float*)d_in[19];
    const float* hb2     = (const float*)d_in[20];
    float* out = (float*)d_out;

    float* ws   = (float*)d_ws;
    float* h    = ws;
    float* h2   = h + (size_t)N_ * 128;
    float* te   = h2 + (size_t)N_ * 128;
    float* al_s = te + (size_t)N_ * 16;
    float* al_d = al_s + (size_t)N_ * 4;
    float* gate = al_d + (size_t)N_ * 4;
    int* indptr = (int*)(gate + N_);
    int* srcs   = indptr + (N_ + 1);
    int* count  = srcs + (N_ + E_);
    int* cursor = count + N_;
    int* cbase  = cursor + N_;
    int* minmax = cbase + 1025;

    k_init_minmax<<<1, 1, 0, stream>>>(minmax);
    k_prep<<<(N_ + 255) / 256, 256, 0, stream>>>(ts, te, count, minmax);
    k_count<<<(E_ + 255) / 256, 256, 0, stream>>>(ei, count);
    k_scan_a<<<1, 1024, 0, stream>>>(count, cbase);
    k_scan_b<<<4, 256, 0, stream>>>(count, cbase, indptr, srcs, cursor);
    k_scatter<<<(E_ + 255) / 256, 256, 0, stream>>>(ei, cursor, srcs);
    k_gate<<<(N_ + 255) / 256, 256, 0, stream>>>(ts, minmax, gw1, gb1, gw2, gb2, gate);

    k_gemm<144, 128, 0><<<782, 256, 0, stream>>>(x, te, proj_w, proj_b, nullptr, nullptr,
                                                 nullptr, nullptr, h, nullptr, nullptr);
    for (int l = 0; l < 2; ++l) {
        k_gemm<128, 128, 1><<<782, 256, 0, stream>>>(h, nullptr, conv_w + l * 128 * 128, nullptr,
                                                     att_src + l * 128, att_dst + l * 128,
                                                     nullptr, nullptr, h2, al_s, al_d);
        k_gat<<<N_, 128, 0, stream>>>(indptr, srcs, al_s, al_d, h2, conv_b + l * 128,
                                      bn_g + l * 128, bn_b + l * 128, bn_m + l * 128, bn_v + l * 128,
                                      gate, h);
    }
    k_gemm<128, 64, 2><<<782, 256, 0, stream>>>(h, nullptr, hw1, hb1, nullptr, nullptr,
                                                hw2, hb2, out, nullptr, nullptr);
}

// Round 3
// 510.104 us; speedup vs baseline: 1.9618x; 1.5432x over previous
//
#include <hip/hip_runtime.h>
#include <cfloat>
#include <climits>
#include <cmath>

constexpr int N_ = 100000;
constexpr int E_ = 800000;
constexpr int NBLK_ = (N_ + 255) / 256;  // 391

// ---------------- init ----------------
__global__ void k_init_minmax(int* minmax) {
    minmax[0] = INT_MAX;
    minmax[1] = INT_MIN;
}

// time encoding + count init + t min/max
__global__ __launch_bounds__(256) void k_prep(const int* __restrict__ ts, float* __restrict__ te,
                                              int* __restrict__ count, int* __restrict__ minmax) {
    const float FRQ[8] = {1.0f, 0.31622776601683794f, 0.1f, 0.031622776601683794f,
                          0.01f, 0.0031622776601683794f, 0.001f, 0.00031622776601683794f};
    int n = blockIdx.x * 256 + threadIdx.x;
    int tv_min = INT_MAX, tv_max = INT_MIN;
    if (n < N_) {
        int tv = ts[n];
        tv_min = tv; tv_max = tv;
        count[n] = 1;  // self loop
        float tf = (float)tv;
#pragma unroll
        for (int j = 0; j < 8; ++j) {
            float ph = tf * FRQ[j];
            te[n * 16 + j] = sinf(ph);
            te[n * 16 + 8 + j] = cosf(ph);
        }
    }
#pragma unroll
    for (int o = 32; o >= 1; o >>= 1) {
        tv_min = min(tv_min, __shfl_xor(tv_min, o));
        tv_max = max(tv_max, __shfl_xor(tv_max, o));
    }
    if ((threadIdx.x & 63) == 0) {
        atomicMin(&minmax[0], tv_min);
        atomicMax(&minmax[1], tv_max);
    }
}

__global__ __launch_bounds__(256) void k_count(const int* __restrict__ ei, int* __restrict__ count) {
    int e = blockIdx.x * 256 + threadIdx.x;
    if (e < E_) atomicAdd(&count[ei[E_ + e]], 1);
}

// ---- multi-block exclusive scan of count[N] ----
__global__ __launch_bounds__(256) void k_bsum(const int* __restrict__ count, int* __restrict__ bsum) {
    int i = blockIdx.x * 256 + threadIdx.x;
    int v = (i < N_) ? count[i] : 0;
#pragma unroll
    for (int o = 32; o >= 1; o >>= 1) v += __shfl_xor(v, o);
    __shared__ int wsum[4];
    if ((threadIdx.x & 63) == 0) wsum[threadIdx.x >> 6] = v;
    __syncthreads();
    if (threadIdx.x == 0) bsum[blockIdx.x] = wsum[0] + wsum[1] + wsum[2] + wsum[3];
}

__global__ __launch_bounds__(512) void k_bscan(int* __restrict__ bsum, int* __restrict__ indptr) {
    int t = threadIdx.x;
    int v = (t < NBLK_) ? bsum[t] : 0;
    __shared__ int sc[512];
    sc[t] = v;
    __syncthreads();
    for (int o = 1; o < 512; o <<= 1) {
        int u = (t >= o) ? sc[t - o] : 0;
        __syncthreads();
        sc[t] += u;
        __syncthreads();
    }
    if (t < NBLK_) bsum[t] = sc[t] - v;  // exclusive
    if (t == NBLK_ - 1) indptr[N_] = sc[t];
}

__global__ __launch_bounds__(256) void k_scan_c(const int* __restrict__ count, const int* __restrict__ bsum,
                                                int* __restrict__ indptr, int* __restrict__ srcs,
                                                int* __restrict__ cursor) {
    int t = threadIdx.x;
    int i = blockIdx.x * 256 + t;
    int v = (i < N_) ? count[i] : 0;
    __shared__ int sc[256];
    sc[t] = v;
    __syncthreads();
    for (int o = 1; o < 256; o <<= 1) {
        int u = (t >= o) ? sc[t - o] : 0;
        __syncthreads();
        sc[t] += u;
        __syncthreads();
    }
    if (i < N_) {
        int off = bsum[blockIdx.x] + sc[t] - v;
        indptr[i] = off;
        srcs[off] = i;        // self loop first
        cursor[i] = off + 1;
    }
}

__global__ __launch_bounds__(256) void k_scatter(const int* __restrict__ ei, int* __restrict__ cursor,
                                                 int* __restrict__ srcs) {
    int e = blockIdx.x * 256 + threadIdx.x;
    if (e < E_) {
        int s = ei[e];
        int d = ei[E_ + e];
        int p = atomicAdd(&cursor[d], 1);
        srcs[p] = s;
    }
}

__global__ __launch_bounds__(256) void k_gate(const int* __restrict__ ts, const int* __restrict__ minmax,
                                              const float* __restrict__ gw1, const float* __restrict__ gb1,
                                              const float* __restrict__ gw2, const float* __restrict__ gb2,
                                              float* __restrict__ gate) {
    int n = blockIdx.x * 256 + threadIdx.x;
    if (n >= N_) return;
    float mn = (float)minmax[0], mx = (float)minmax[1];
    float age = ((float)ts[n] - mn) / fmaxf(mx - mn, 1.0f);
    float o = gb2[0];
#pragma unroll
    for (int j = 0; j < 16; ++j) {
        float hj = fmaxf(age * gw1[j] + gb1[j], 0.f);
        o += hj * gw2[j];
    }
    gate[n] = 1.f / (1.f + __expf(-o));
}

// ---------------- fused fp32 GEMM, 128-row tile, 8x8 per-thread blocking ----------------
template <int K, int M, int MODE>
__global__ __launch_bounds__(256) void k_gemm(const float* __restrict__ A, const float* __restrict__ te,
                                              const float* __restrict__ W, const float* __restrict__ bias,
                                              const float* __restrict__ asrc, const float* __restrict__ adst,
                                              const float* __restrict__ w2, const float* __restrict__ b2,
                                              float* __restrict__ Cout, float* __restrict__ al_s,
                                              float* __restrict__ al_d) {
    constexpr int GR = 128, KC = 16;
    constexpr int NS = M / 64;
    __shared__ float As[KC][GR + 4];
    __shared__ float Ws[KC][M];
    __shared__ float asl[128], adl[128];
    __shared__ float w2l[128];
    const int r0 = blockIdx.x * GR;
    const int tid = threadIdx.x;
    const int tx = tid & 15, ty = tid >> 4;
    if (MODE == 1 && tid < 128) { asl[tid] = asrc[tid]; adl[tid] = adst[tid]; }
    if (MODE == 2 && tid < 128) { w2l[tid] = w2[tid]; }
    float acc[8][NS * 4];
#pragma unroll
    for (int i = 0; i < 8; ++i)
#pragma unroll
        for (int j = 0; j < NS * 4; ++j) acc[i][j] = 0.f;

    for (int k0 = 0; k0 < K; k0 += KC) {
        __syncthreads();
#pragma unroll
        for (int i = 0; i < 2; ++i) {
            int f = tid * 2 + i;
            int row = f >> 2, fq = f & 3;
            int gr = r0 + row;
            float4 v = make_float4(0.f, 0.f, 0.f, 0.f);
            if (gr < N_) {
                if (MODE == 0) {
                    if (k0 < 128) v = *(const float4*)&A[gr * 128 + k0 + fq * 4];
                    else          v = *(const float4*)&te[gr * 16 + fq * 4];
                } else {
                    v = *(const float4*)&A[gr * K + k0 + fq * 4];
                }
            }
            As[fq * 4 + 0][row] = v.x;
            As[fq * 4 + 1][row] = v.y;
            As[fq * 4 + 2][row] = v.z;
            As[fq * 4 + 3][row] = v.w;
        }
#pragma unroll
        for (int i = 0; i < (KC * M / 4) / 256; ++i) {
            int f = tid + i * 256;
            int kk = f / (M / 4), c4 = f % (M / 4);
            *(float4*)&Ws[kk][c4 * 4] = *(const float4*)&W[(k0 + kk) * M + c4 * 4];
        }
        __syncthreads();
#pragma unroll
        for (int kk = 0; kk < KC; ++kk) {
            float4 a0 = *(const float4*)&As[kk][ty * 8];
            float4 a1 = *(const float4*)&As[kk][ty * 8 + 4];
            float av[8] = {a0.x, a0.y, a0.z, a0.w, a1.x, a1.y, a1.z, a1.w};
            float wv[NS * 4];
#pragma unroll
            for (int s = 0; s < NS; ++s) {
                float4 w = *(const float4*)&Ws[kk][s * 64 + tx * 4];
                wv[s * 4 + 0] = w.x; wv[s * 4 + 1] = w.y;
                wv[s * 4 + 2] = w.z; wv[s * 4 + 3] = w.w;
            }
#pragma unroll
            for (int i = 0; i < 8; ++i)
#pragma unroll
                for (int j = 0; j < NS * 4; ++j) acc[i][j] = fmaf(av[i], wv[j], acc[i][j]);
        }
    }

#pragma unroll
    for (int i = 0; i < 8; ++i) {
        int gr = r0 + ty * 8 + i;
        bool valid = gr < N_;
        if (MODE == 0) {
            if (valid) {
#pragma unroll
                for (int s = 0; s < NS; ++s) {
                    float4 v;
                    v.x = fmaxf(acc[i][s * 4 + 0] + bias[s * 64 + tx * 4 + 0], 0.f);
                    v.y = fmaxf(acc[i][s * 4 + 1] + bias[s * 64 + tx * 4 + 1], 0.f);
                    v.z = fmaxf(acc[i][s * 4 + 2] + bias[s * 64 + tx * 4 + 2], 0.f);
                    v.w = fmaxf(acc[i][s * 4 + 3] + bias[s * 64 + tx * 4 + 3], 0.f);
                    *(float4*)&Cout[gr * M + s * 64 + tx * 4] = v;
                }
            }
        } else if (MODE == 1) {
            if (valid) {
#pragma unroll
                for (int s = 0; s < NS; ++s) {
                    float4 v = make_float4(acc[i][s * 4 + 0], acc[i][s * 4 + 1],
                                           acc[i][s * 4 + 2], acc[i][s * 4 + 3]);
                    *(float4*)&Cout[gr * M + s * 64 + tx * 4] = v;
                }
            }
#pragma unroll
            for (int s = 0; s < NS; ++s) {
                float ps = 0.f, pd = 0.f;
#pragma unroll
                for (int q = 0; q < 4; ++q) {
                    int c = s * 64 + tx * 4 + q;
                    ps = fmaf(acc[i][s * 4 + q], asl[c], ps);
                    pd = fmaf(acc[i][s * 4 + q], adl[c], pd);
                }
#pragma unroll
                for (int o = 1; o <= 4; o <<= 1) {
                    ps += __shfl_xor(ps, o);
                    pd += __shfl_xor(pd, o);
                }
                if (valid && (tx & 7) == 0) {
                    int head = 2 * s + (tx >> 3);
                    al_s[gr * 4 + head] = ps;
                    al_d[gr * 4 + head] = pd;
                }
            }
        } else {
            float ps0 = 0.f, ps1 = 0.f;
#pragma unroll
            for (int q = 0; q < 4; ++q) {
                float hv = fmaxf(acc[i][q] + bias[tx * 4 + q], 0.f);
                int c = tx * 4 + q;
                ps0 = fmaf(hv, w2l[c * 2 + 0], ps0);
                ps1 = fmaf(hv, w2l[c * 2 + 1], ps1);
            }
#pragma unroll
            for (int o = 1; o <= 8; o <<= 1) {
                ps0 += __shfl_xor(ps0, o);
                ps1 += __shfl_xor(ps1, o);
            }
            if (valid && tx == 0) {
                *(float2*)&Cout[gr * 2] = make_float2(ps0 + b2[0], ps1 + b2[1]);
            }
        }
    }
}

// ---------------- GAT aggregation: 32-lane group per node, barrier-free ----------------
// 8 nodes per 256-thread block. Lane owns 4 channels (float4). Softmax state in
// registers; per-edge (w, src) broadcast via width-32 shuffles. No LDS, no syncthreads.
__global__ __launch_bounds__(256) void k_gat(const int* __restrict__ indptr, const int* __restrict__ srcs,
                                             const float* __restrict__ al_s, const float* __restrict__ al_d,
                                             const float* __restrict__ h2, const float* __restrict__ convb,
                                             const float* __restrict__ gamma, const float* __restrict__ beta,
                                             const float* __restrict__ mean, const float* __restrict__ var,
                                             const float* __restrict__ gate, float* __restrict__ hout) {
    int g = threadIdx.x >> 5, lg = threadIdx.x & 31;
    int n = blockIdx.x * 8 + g;
    if (n >= N_) return;
    int start = indptr[n], end = indptr[n + 1];
    int hl = lg >> 3;        // head of my 4 channels
    int c0 = lg * 4;         // first channel
    float4 ad4 = *(const float4*)&al_d[n * 4];
    float adv[4] = {ad4.x, ad4.y, ad4.z, ad4.w};
    float M[4] = {-FLT_MAX, -FLT_MAX, -FLT_MAX, -FLT_MAX};
    float D[4] = {0.f, 0.f, 0.f, 0.f};
    float ac0 = 0.f, ac1 = 0.f, ac2 = 0.f, ac3 = 0.f;

    for (int p0 = start; p0 < end; p0 += 32) {
        int cs = end - p0;
        if (cs > 32) cs = 32;
        float a[4];
        int s = 0;
        if (lg < cs) {
            s = srcs[p0 + lg];
            float4 as4 = *(const float4*)&al_s[s * 4];
            float asv[4] = {as4.x, as4.y, as4.z, as4.w};
#pragma unroll
            for (int h = 0; h < 4; ++h) {
                float x = asv[h] + adv[h];
                a[h] = x > 0.f ? x : 0.2f * x;
            }
        } else {
#pragma unroll
            for (int h = 0; h < 4; ++h) a[h] = -FLT_MAX;
        }
        float f[4], w[4];
#pragma unroll
        for (int h = 0; h < 4; ++h) {
            float m = a[h];
#pragma unroll
            for (int o = 16; o >= 1; o >>= 1) m = fmaxf(m, __shfl_xor(m, o));
            float Mn = fmaxf(M[h], m);
            f[h] = __expf(M[h] - Mn);
            M[h] = Mn;
            w[h] = __expf(a[h] - Mn);   // lanes >= cs give exp(-huge) = 0
            float sv = w[h];
#pragma unroll
            for (int o = 16; o >= 1; o >>= 1) sv += __shfl_xor(sv, o);
            D[h] = D[h] * f[h] + sv;
        }
        float fh = hl < 2 ? (hl == 0 ? f[0] : f[1]) : (hl == 2 ? f[2] : f[3]);
        float whl = hl < 2 ? (hl == 0 ? w[0] : w[1]) : (hl == 2 ? w[2] : w[3]);
        ac0 *= fh; ac1 *= fh; ac2 *= fh; ac3 *= fh;
        int i = 0;
        for (; i + 1 < cs; i += 2) {
            float w0 = __shfl(whl, i, 32);
            float w1 = __shfl(whl, i + 1, 32);
            int s0 = __shfl(s, i, 32);
            int s1 = __shfl(s, i + 1, 32);
            float4 h0 = *(const float4*)&h2[s0 * 128 + c0];
            float4 h1 = *(const float4*)&h2[s1 * 128 + c0];
            ac0 = fmaf(w0, h0.x, ac0); ac1 = fmaf(w0, h0.y, ac1);
            ac2 = fmaf(w0, h0.z, ac2); ac3 = fmaf(w0, h0.w, ac3);
            ac0 = fmaf(w1, h1.x, ac0); ac1 = fmaf(w1, h1.y, ac1);
            ac2 = fmaf(w1, h1.z, ac2); ac3 = fmaf(w1, h1.w, ac3);
        }
        if (i < cs) {
            float w0 = __shfl(whl, i, 32);
            int s0 = __shfl(s, i, 32);
            float4 h0 = *(const float4*)&h2[s0 * 128 + c0];
            ac0 = fmaf(w0, h0.x, ac0); ac1 = fmaf(w0, h0.y, ac1);
            ac2 = fmaf(w0, h0.z, ac2); ac3 = fmaf(w0, h0.w, ac3);
        }
    }

    float Dh = hl < 2 ? (hl == 0 ? D[0] : D[1]) : (hl == 2 ? D[2] : D[3]);
    float rd = 1.0f / (Dh + 1e-16f);
    float gn = gate[n];
    float4 cb = *(const float4*)&convb[c0];
    float4 gm = *(const float4*)&gamma[c0];
    float4 bt = *(const float4*)&beta[c0];
    float4 mu = *(const float4*)&mean[c0];
    float4 vr = *(const float4*)&var[c0];
    float accs[4] = {ac0, ac1, ac2, ac3};
    float cbv[4] = {cb.x, cb.y, cb.z, cb.w};
    float gmv[4] = {gm.x, gm.y, gm.z, gm.w};
    float btv[4] = {bt.x, bt.y, bt.z, bt.w};
    float muv[4] = {mu.x, mu.y, mu.z, mu.w};
    float vrv[4] = {vr.x, vr.y, vr.z, vr.w};
    float4 outv;
    float* ov = (float*)&outv;
#pragma unroll
    for (int q = 0; q < 4; ++q) {
        float val = accs[q] * rd + cbv[q];
        float sc = gmv[q] * rsqrtf(vrv[q] + 1e-5f);
        val = (val - muv[q]) * sc + btv[q];
        val = val > 0.f ? val : expm1f(val);
        ov[q] = val * gn;
    }
    *(float4*)&hout[n * 128 + c0] = outv;
}

extern "C" void kernel_launch(void* const* d_in, const int* in_sizes, int n_in,
                              void* d_out, int out_size, void* d_ws, size_t ws_size,
                              hipStream_t stream) {
    const float* x       = (const float*)d_in[0];
    const int*   ei      = (const int*)d_in[1];
    const int*   ts      = (const int*)d_in[2];
    const float* proj_w  = (const float*)d_in[3];
    const float* proj_b  = (const float*)d_in[4];
    const float* conv_w  = (const float*)d_in[5];
    const float* conv_b  = (const float*)d_in[6];
    const float* att_src = (const float*)d_in[7];
    const float* att_dst = (const float*)d_in[8];
    const float* bn_g    = (const float*)d_in[9];
    const float* bn_b    = (const float*)d_in[10];
    const float* bn_m    = (const float*)d_in[11];
    const float* bn_v    = (const float*)d_in[12];
    const float* gw1     = (const float*)d_in[13];
    const float* gb1     = (const float*)d_in[14];
    const float* gw2     = (const float*)d_in[15];
    const float* gb2     = (const float*)d_in[16];
    const float* hw1     = (const float*)d_in[17];
    const float* hb1     = (const float*)d_in[18];
    const float* hw2     = (const float*)d_in[19];
    const float* hb2     = (const float*)d_in[20];
    float* out = (float*)d_out;

    float* ws   = (float*)d_ws;
    float* h    = ws;
    float* h2   = h + (size_t)N_ * 128;
    float* te   = h2 + (size_t)N_ * 128;
    float* al_s = te + (size_t)N_ * 16;
    float* al_d = al_s + (size_t)N_ * 4;
    float* gate = al_d + (size_t)N_ * 4;
    int* indptr = (int*)(gate + N_);
    int* srcs   = indptr + (N_ + 1);
    int* count  = srcs + (N_ + E_);
    int* cursor = count + N_;
    int* bsum   = cursor + N_;
    int* minmax = bsum + NBLK_ + 1;

    k_init_minmax<<<1, 1, 0, stream>>>(minmax);
    k_prep<<<(N_ + 255) / 256, 256, 0, stream>>>(ts, te, count, minmax);
    k_count<<<(E_ + 255) / 256, 256, 0, stream>>>(ei, count);
    k_bsum<<<NBLK_, 256, 0, stream>>>(count, bsum);
    k_bscan<<<1, 512, 0, stream>>>(bsum, indptr);
    k_scan_c<<<NBLK_, 256, 0, stream>>>(count, bsum, indptr, srcs, cursor);
    k_scatter<<<(E_ + 255) / 256, 256, 0, stream>>>(ei, cursor, srcs);
    k_gate<<<(N_ + 255) / 256, 256, 0, stream>>>(ts, minmax, gw1, gb1, gw2, gb2, gate);

    k_gemm<144, 128, 0><<<782, 256, 0, stream>>>(x, te, proj_w, proj_b, nullptr, nullptr,
                                                 nullptr, nullptr, h, nullptr, nullptr);
    for (int l = 0; l < 2; ++l) {
        k_gemm<128, 128, 1><<<782, 256, 0, stream>>>(h, nullptr, conv_w + l * 128 * 128, nullptr,
                                                     att_src + l * 128, att_dst + l * 128,
                                                     nullptr, nullptr, h2, al_s, al_d);
        k_gat<<<(N_ + 7) / 8, 256, 0, stream>>>(indptr, srcs, al_s, al_d, h2, conv_b + l * 128,
                                                bn_g + l * 128, bn_b + l * 128, bn_m + l * 128,
                                                bn_v + l * 128, gate, h);
    }
    k_gemm<128, 64, 2><<<782, 256, 0, stream>>>(h, nullptr, hw1, hb1, nullptr, nullptr,
                                                hw2, hb2, out, nullptr, nullptr);
}